// Round 1
// baseline (869.123 us; speedup 1.0000x reference)
//
#include <hip/hip_runtime.h>
#include <math.h>

#define N_NODES 50000
#define N_GRAPHS 500
#define NPG 100
#define N_EDGES 500000
#define F_IN 16
#define HID 64

#define SELU_SCALE 1.0507009873554804934193349852946f
#define SELU_ALPHA 1.6732632423543772848170429916717f

__device__ __forceinline__ float lrelu(float x){ return x > 0.f ? x : 0.2f * x; }
__device__ __forceinline__ float eluf(float x){ return x > 0.f ? x : expf(x) - 1.f; }
__device__ __forceinline__ float seluf(float x){
    return x > 0.f ? SELU_SCALE * x : SELU_SCALE * (SELU_ALPHA * (expf(x) - 1.f));
}

// ---------------- CSR build ----------------
__global__ void k_count(const int* __restrict__ dst, int* __restrict__ counts){
    int e = blockIdx.x * 256 + threadIdx.x;
    if (e < N_EDGES) atomicAdd(&counts[dst[e]], 1);
}

__global__ void k_local_scan(const int* __restrict__ counts, int* __restrict__ local_off,
                             int* __restrict__ graph_tot){
    __shared__ int s[128];
    int g = blockIdx.x, t = threadIdx.x;
    int v = (t < NPG) ? counts[g * NPG + t] : 0;
    s[t] = v; __syncthreads();
    for (int o = 1; o < 128; o <<= 1){
        int x = (t >= o) ? s[t - o] : 0;
        __syncthreads();
        s[t] += x;
        __syncthreads();
    }
    if (t < NPG) local_off[g * NPG + t] = s[t] - v;   // exclusive
    if (t == 127) graph_tot[g] = s[127];
}

__global__ void k_graph_scan(const int* __restrict__ graph_tot, int* __restrict__ graph_base){
    __shared__ int s[512];
    int t = threadIdx.x;
    int v = (t < N_GRAPHS) ? graph_tot[t] : 0;
    s[t] = v; __syncthreads();
    for (int o = 1; o < 512; o <<= 1){
        int x = (t >= o) ? s[t - o] : 0;
        __syncthreads();
        s[t] += x;
        __syncthreads();
    }
    if (t < N_GRAPHS) graph_base[t] = s[t] - v;       // exclusive
}

__global__ void k_off(const int* __restrict__ local_off, const int* __restrict__ graph_base,
                      int* __restrict__ node_off, int* __restrict__ write_ptr){
    int n = blockIdx.x * 256 + threadIdx.x;
    if (n < N_NODES){
        int v = local_off[n] + graph_base[n / NPG];
        node_off[n] = v;
        write_ptr[n] = v;
    }
}

__global__ void k_scatter(const int* __restrict__ src, const int* __restrict__ dst,
                          int* __restrict__ write_ptr, int* __restrict__ csr){
    int e = blockIdx.x * 256 + threadIdx.x;
    if (e < N_EDGES){
        int d = dst[e];
        int pos = atomicAdd(&write_ptr[d], 1);
        csr[pos] = src[e];
    }
}

// ---------------- GraphNorm ----------------
__global__ void k_gnorm(const float* __restrict__ x, const float* __restrict__ w,
                        const float* __restrict__ b, const float* __restrict__ ms,
                        float* __restrict__ y){
    __shared__ float sx[NPG * F_IN];
    __shared__ float red[16][16];
    __shared__ float meanS[16], varS[16];
    int g = blockIdx.x, t = threadIdx.x;
    for (int idx = t; idx < NPG * F_IN; idx += 256) sx[idx] = x[g * NPG * F_IN + idx];
    __syncthreads();
    int f = t & 15, grp = t >> 4;
    float p = 0.f;
    for (int i = grp; i < NPG; i += 16) p += sx[i * 16 + f];
    red[grp][f] = p; __syncthreads();
    if (t < 16){
        float s = 0.f;
        for (int i = 0; i < 16; i++) s += red[i][t];
        meanS[t] = s * (1.f / 100.f);
    }
    __syncthreads();
    float mm = meanS[f] * ms[f];
    p = 0.f;
    for (int i = grp; i < NPG; i += 16){ float v = sx[i * 16 + f] - mm; p += v * v; }
    red[grp][f] = p; __syncthreads();
    if (t < 16){
        float s = 0.f;
        for (int i = 0; i < 16; i++) s += red[i][t];
        varS[t] = s * (1.f / 100.f);
    }
    __syncthreads();
    for (int idx = t; idx < NPG * F_IN; idx += 256){
        int ff = idx & 15;
        float v = sx[idx] - meanS[ff] * ms[ff];
        y[g * NPG * F_IN + idx] = w[ff] * v * rsqrtf(varS[ff] + 1e-5f) + b[ff];
    }
}

// ---------------- tiled fp32 GEMM: Y[N,OUT] = X[N,K] @ W[K,OUT] ----------------
// block 256 threads, tile 64 rows x 64 cols, K-tile 16, 4x4 register blocking
__global__ void k_gemm_tiled(const float* __restrict__ X, const float* __restrict__ W,
                             float* __restrict__ Y, int N, int K, int OUT){
    __shared__ float As[16][68];
    __shared__ float Bs[16][68];
    int t = threadIdx.x;
    int r0 = blockIdx.y * 64;
    int c0 = blockIdx.x * 64;
    int tx = t & 15, ty = t >> 4;
    float acc[4][4];
    #pragma unroll
    for (int i = 0; i < 4; i++)
        #pragma unroll
        for (int j = 0; j < 4; j++) acc[i][j] = 0.f;

    int lk = t & 15;       // A-load: k
    int lm0 = t >> 4;      // A-load: row base
    int ln = t & 63;       // B-load: n
    int lkb = t >> 6;      // B-load: k base

    for (int kt = 0; kt < K; kt += 16){
        #pragma unroll
        for (int i = 0; i < 4; i++){
            int m = lm0 + i * 16;
            int row = r0 + m;
            As[lk][m] = (row < N) ? X[row * K + kt + lk] : 0.f;
        }
        #pragma unroll
        for (int i = 0; i < 4; i++){
            int k = lkb + i * 4;
            Bs[k][ln] = W[(kt + k) * OUT + c0 + ln];
        }
        __syncthreads();
        #pragma unroll
        for (int k = 0; k < 16; k++){
            float4 a = *(const float4*)&As[k][ty * 4];
            float4 b = *(const float4*)&Bs[k][tx * 4];
            float av[4] = {a.x, a.y, a.z, a.w};
            float bv[4] = {b.x, b.y, b.z, b.w};
            #pragma unroll
            for (int i = 0; i < 4; i++)
                #pragma unroll
                for (int j = 0; j < 4; j++) acc[i][j] += av[i] * bv[j];
        }
        __syncthreads();
    }
    #pragma unroll
    for (int i = 0; i < 4; i++){
        int row = r0 + ty * 4 + i;
        if (row < N){
            float4 v = make_float4(acc[i][0], acc[i][1], acc[i][2], acc[i][3]);
            *(float4*)&Y[row * OUT + c0 + tx * 4] = v;
        }
    }
}

// ---------------- attention logits ----------------
// H=4, C=64: a_src[n,h] = sum_c h[n,h,c]*as[h,c]
__global__ void k_att4(const float* __restrict__ h, const float* __restrict__ as,
                       const float* __restrict__ ad, float* __restrict__ asrc,
                       float* __restrict__ adst){
    int wave = threadIdx.x >> 6, lane = threadIdx.x & 63;
    int n = blockIdx.x * 4 + wave;
    if (n >= N_NODES) return;
    float ps[4], pd[4];
    #pragma unroll
    for (int hh = 0; hh < 4; hh++){
        float v = h[n * 256 + hh * 64 + lane];
        ps[hh] = v * as[hh * 64 + lane];
        pd[hh] = v * ad[hh * 64 + lane];
    }
    #pragma unroll
    for (int o = 32; o >= 1; o >>= 1){
        #pragma unroll
        for (int hh = 0; hh < 4; hh++){
            ps[hh] += __shfl_xor(ps[hh], o);
            pd[hh] += __shfl_xor(pd[hh], o);
        }
    }
    if (lane == 0){
        *(float4*)&asrc[n * 4] = make_float4(ps[0], ps[1], ps[2], ps[3]);
        *(float4*)&adst[n * 4] = make_float4(pd[0], pd[1], pd[2], pd[3]);
    }
}

// H=1, C=64
__global__ void k_att1(const float* __restrict__ h, const float* __restrict__ as,
                       const float* __restrict__ ad, float* __restrict__ asrc,
                       float* __restrict__ adst){
    int wave = threadIdx.x >> 6, lane = threadIdx.x & 63;
    int n = blockIdx.x * 4 + wave;
    if (n >= N_NODES) return;
    float v = h[n * 64 + lane];
    float ps = v * as[lane];
    float pd = v * ad[lane];
    #pragma unroll
    for (int o = 32; o >= 1; o >>= 1){
        ps += __shfl_xor(ps, o);
        pd += __shfl_xor(pd, o);
    }
    if (lane == 0){ asrc[n] = ps; adst[n] = pd; }
}

// ---------------- softmax aggregation ----------------
// H=4, C=64. One wave per dst node. Includes self-loop. out = agg + bias, optional ELU.
__global__ void k_agg4(const float* __restrict__ h, const float* __restrict__ asrc,
                       const float* __restrict__ adst, const int* __restrict__ csr,
                       const int* __restrict__ noff, const int* __restrict__ cnt,
                       const float* __restrict__ bias, float* __restrict__ out, int do_elu){
    int wave = threadIdx.x >> 6, lane = threadIdx.x & 63;
    int d = blockIdx.x * 4 + wave;
    if (d >= N_NODES) return;
    float4 ad = *(const float4*)&adst[d * 4];
    float4 asf = *(const float4*)&asrc[d * 4];
    float e0 = lrelu(asf.x + ad.x), e1 = lrelu(asf.y + ad.y);
    float e2 = lrelu(asf.z + ad.z), e3 = lrelu(asf.w + ad.w);
    float m0 = e0, m1 = e1, m2 = e2, m3 = e3;
    int beg = noff[d], n = cnt[d];
    for (int j = 0; j < n; j++){
        int s = csr[beg + j];
        float4 av = *(const float4*)&asrc[s * 4];
        m0 = fmaxf(m0, lrelu(av.x + ad.x));
        m1 = fmaxf(m1, lrelu(av.y + ad.y));
        m2 = fmaxf(m2, lrelu(av.z + ad.z));
        m3 = fmaxf(m3, lrelu(av.w + ad.w));
    }
    float s0 = expf(e0 - m0), s1 = expf(e1 - m1), s2 = expf(e2 - m2), s3 = expf(e3 - m3);
    for (int j = 0; j < n; j++){
        int s = csr[beg + j];
        float4 av = *(const float4*)&asrc[s * 4];
        s0 += expf(lrelu(av.x + ad.x) - m0);
        s1 += expf(lrelu(av.y + ad.y) - m1);
        s2 += expf(lrelu(av.z + ad.z) - m2);
        s3 += expf(lrelu(av.w + ad.w) - m3);
    }
    float r0 = 1.f / s0, r1 = 1.f / s1, r2 = 1.f / s2, r3 = 1.f / s3;
    int dbase = d * 256 + lane;
    float acc0 = expf(e0 - m0) * r0 * h[dbase];
    float acc1 = expf(e1 - m1) * r1 * h[dbase + 64];
    float acc2 = expf(e2 - m2) * r2 * h[dbase + 128];
    float acc3 = expf(e3 - m3) * r3 * h[dbase + 192];
    for (int j = 0; j < n; j++){
        int s = csr[beg + j];
        float4 av = *(const float4*)&asrc[s * 4];
        int base = s * 256 + lane;
        acc0 += expf(lrelu(av.x + ad.x) - m0) * r0 * h[base];
        acc1 += expf(lrelu(av.y + ad.y) - m1) * r1 * h[base + 64];
        acc2 += expf(lrelu(av.z + ad.z) - m2) * r2 * h[base + 128];
        acc3 += expf(lrelu(av.w + ad.w) - m3) * r3 * h[base + 192];
    }
    float o0 = acc0 + bias[lane];
    float o1 = acc1 + bias[64 + lane];
    float o2 = acc2 + bias[128 + lane];
    float o3 = acc3 + bias[192 + lane];
    if (do_elu){ o0 = eluf(o0); o1 = eluf(o1); o2 = eluf(o2); o3 = eluf(o3); }
    out[dbase] = o0; out[dbase + 64] = o1; out[dbase + 128] = o2; out[dbase + 192] = o3;
}

// H=1, C=64. No ELU (conv3).
__global__ void k_agg1(const float* __restrict__ h, const float* __restrict__ asrc,
                       const float* __restrict__ adst, const int* __restrict__ csr,
                       const int* __restrict__ noff, const int* __restrict__ cnt,
                       const float* __restrict__ bias, float* __restrict__ out){
    int wave = threadIdx.x >> 6, lane = threadIdx.x & 63;
    int d = blockIdx.x * 4 + wave;
    if (d >= N_NODES) return;
    float ad = adst[d];
    float eself = lrelu(asrc[d] + ad);
    float m = eself;
    int beg = noff[d], n = cnt[d];
    for (int j = 0; j < n; j++){
        int s = csr[beg + j];
        m = fmaxf(m, lrelu(asrc[s] + ad));
    }
    float sum = expf(eself - m);
    for (int j = 0; j < n; j++){
        int s = csr[beg + j];
        sum += expf(lrelu(asrc[s] + ad) - m);
    }
    float r = 1.f / sum;
    float acc = expf(eself - m) * r * h[d * 64 + lane];
    for (int j = 0; j < n; j++){
        int s = csr[beg + j];
        acc += expf(lrelu(asrc[s] + ad) - m) * r * h[s * 64 + lane];
    }
    out[d * 64 + lane] = acc + bias[lane];
}

// ---------------- pooling + BN + dense head ----------------
__global__ void k_head(const float* __restrict__ x3, const float* __restrict__ gin,
                       const float* __restrict__ bn_g, const float* __restrict__ bn_b,
                       const float* __restrict__ bn_m, const float* __restrict__ bn_v,
                       const float* __restrict__ Wd1, const float* __restrict__ bd1,
                       const float* __restrict__ Wd2, const float* __restrict__ bd2,
                       const float* __restrict__ Wo, const float* __restrict__ bo,
                       float* __restrict__ out){
    __shared__ float red[256];
    __shared__ float gv[68];
    __shared__ float g2[64];
    __shared__ float g3[64];
    int g = blockIdx.x, t = threadIdx.x;
    int c = t & 63, grp = t >> 6;
    float p = 0.f;
    for (int i = grp; i < NPG; i += 4) p += x3[(g * NPG + i) * 64 + c];
    red[t] = p; __syncthreads();
    if (t < 64){
        float s = red[t] + red[t + 64] + red[t + 128] + red[t + 192];
        float mean = s * (1.f / 100.f);
        gv[t] = (mean - bn_m[t]) * rsqrtf(bn_v[t] + 1e-5f) * bn_g[t] + bn_b[t];
    } else if (t < 68){
        int j = t - 64;
        float v = gin[g * 4 + j];
        gv[t] = (v - bn_m[t]) * rsqrtf(bn_v[t] + 1e-5f) * bn_g[t] + bn_b[t];
    }
    __syncthreads();
    if (t < 64){
        float s = bd1[t];
        for (int i = 0; i < 68; i++) s += gv[i] * Wd1[i * 64 + t];
        g2[t] = seluf(s);
    }
    __syncthreads();
    if (t < 64){
        float s = bd2[t];
        for (int i = 0; i < 64; i++) s += g2[i] * Wd2[i * 64 + t];
        g3[t] = seluf(s);
    }
    __syncthreads();
    if (t == 0){
        float l0 = bo[0], l1 = bo[1];
        for (int i = 0; i < 64; i++){ l0 += g3[i] * Wo[i * 2]; l1 += g3[i] * Wo[i * 2 + 1]; }
        float mx = fmaxf(l0, l1);
        float e0 = expf(l0 - mx), e1 = expf(l1 - mx);
        float inv = 1.f / (e0 + e1);
        out[g * 2] = e0 * inv;
        out[g * 2 + 1] = e1 * inv;
    }
}

extern "C" void kernel_launch(void* const* d_in, const int* in_sizes, int n_in,
                              void* d_out, int out_size, void* d_ws, size_t ws_size,
                              hipStream_t stream){
    const float* x   = (const float*)d_in[0];
    const int*   ei  = (const int*)d_in[1];
    const float* gin = (const float*)d_in[2];
    const float* gn_w = (const float*)d_in[4];
    const float* gn_b = (const float*)d_in[5];
    const float* gn_ms = (const float*)d_in[6];
    const float* W1 = (const float*)d_in[7];
    const float* as1 = (const float*)d_in[8];
    const float* ad1 = (const float*)d_in[9];
    const float* b1 = (const float*)d_in[10];
    const float* W2 = (const float*)d_in[11];
    const float* as2 = (const float*)d_in[12];
    const float* ad2 = (const float*)d_in[13];
    const float* b2 = (const float*)d_in[14];
    const float* W3 = (const float*)d_in[15];
    const float* as3 = (const float*)d_in[16];
    const float* ad3 = (const float*)d_in[17];
    const float* b3 = (const float*)d_in[18];
    const float* bn_g = (const float*)d_in[19];
    const float* bn_b = (const float*)d_in[20];
    const float* bn_m = (const float*)d_in[21];
    const float* bn_v = (const float*)d_in[22];
    const float* Wd1 = (const float*)d_in[23];
    const float* bd1 = (const float*)d_in[24];
    const float* Wd2 = (const float*)d_in[25];
    const float* bd2 = (const float*)d_in[26];
    const float* Wo = (const float*)d_in[27];
    const float* bo = (const float*)d_in[28];
    float* out = (float*)d_out;

    const int* src = ei;
    const int* dst = ei + N_EDGES;

    char* ws = (char*)d_ws;
    size_t off = 0;
    auto alloc = [&](size_t bytes) -> void* {
        void* p = ws + off;
        off = (off + bytes + 255) & ~(size_t)255;
        return p;
    };
    int* counts     = (int*)alloc((size_t)N_NODES * 4);
    int* local_off  = (int*)alloc((size_t)N_NODES * 4);
    int* node_off   = (int*)alloc((size_t)N_NODES * 4);
    int* write_ptr  = (int*)alloc((size_t)N_NODES * 4);
    int* graph_tot  = (int*)alloc(512 * 4);
    int* graph_base = (int*)alloc(512 * 4);
    int* csr        = (int*)alloc((size_t)N_EDGES * 4);
    float* y        = (float*)alloc((size_t)N_NODES * F_IN * 4);
    float* asrc     = (float*)alloc((size_t)N_NODES * 4 * 4);
    float* adst     = (float*)alloc((size_t)N_NODES * 4 * 4);
    float* bufA     = (float*)alloc((size_t)N_NODES * 256 * 4);
    float* bufB     = (float*)alloc((size_t)N_NODES * 256 * 4);

    // --- CSR build ---
    hipMemsetAsync(counts, 0, (size_t)N_NODES * 4, stream);
    k_count<<<(N_EDGES + 255) / 256, 256, 0, stream>>>(dst, counts);
    k_local_scan<<<N_GRAPHS, 128, 0, stream>>>(counts, local_off, graph_tot);
    k_graph_scan<<<1, 512, 0, stream>>>(graph_tot, graph_base);
    k_off<<<(N_NODES + 255) / 256, 256, 0, stream>>>(local_off, graph_base, node_off, write_ptr);
    k_scatter<<<(N_EDGES + 255) / 256, 256, 0, stream>>>(src, dst, write_ptr, csr);

    // --- GraphNorm ---
    k_gnorm<<<N_GRAPHS, 256, 0, stream>>>(x, gn_w, gn_b, gn_ms, y);

    int nwb = (N_NODES + 3) / 4;   // node-wave blocks (4 waves/block)
    dim3 gemm_grid4(4, (N_NODES + 63) / 64);
    dim3 gemm_grid1(1, (N_NODES + 63) / 64);

    // --- conv1: 16 -> 4x64, ELU ---
    k_gemm_tiled<<<gemm_grid4, 256, 0, stream>>>(y, W1, bufA, N_NODES, 16, 256);
    k_att4<<<nwb, 256, 0, stream>>>(bufA, as1, ad1, asrc, adst);
    k_agg4<<<nwb, 256, 0, stream>>>(bufA, asrc, adst, csr, node_off, counts, b1, bufB, 1);

    // --- conv2: 256 -> 4x64, ELU ---
    k_gemm_tiled<<<gemm_grid4, 256, 0, stream>>>(bufB, W2, bufA, N_NODES, 256, 256);
    k_att4<<<nwb, 256, 0, stream>>>(bufA, as2, ad2, asrc, adst);
    k_agg4<<<nwb, 256, 0, stream>>>(bufA, asrc, adst, csr, node_off, counts, b2, bufB, 1);

    // --- conv3: 256 -> 64, no ELU ---
    k_gemm_tiled<<<gemm_grid1, 256, 0, stream>>>(bufB, W3, bufA, N_NODES, 256, 64);
    k_att1<<<nwb, 256, 0, stream>>>(bufA, as3, ad3, asrc, adst);
    k_agg1<<<nwb, 256, 0, stream>>>(bufA, asrc, adst, csr, node_off, counts, b3, bufB);

    // --- pool + BN + dense head + softmax ---
    k_head<<<N_GRAPHS, 256, 0, stream>>>(bufB, gin, bn_g, bn_b, bn_m, bn_v,
                                         Wd1, bd1, Wd2, bd2, Wo, bo, out);
}

// Round 2
// 649.690 us; speedup vs baseline: 1.3378x; 1.3378x over previous
//
#include <hip/hip_runtime.h>
#include <math.h>

#define N_NODES 50000
#define N_GRAPHS 500
#define NPG 100
#define N_EDGES 500000
#define F_IN 16
#define HID 64

#define SELU_SCALE 1.0507009873554804934193349852946f
#define SELU_ALPHA 1.6732632423543772848170429916717f

__device__ __forceinline__ float lrelu(float x){ return x > 0.f ? x : 0.2f * x; }
__device__ __forceinline__ float eluf(float x){ return x > 0.f ? x : expf(x) - 1.f; }
__device__ __forceinline__ float seluf(float x){
    return x > 0.f ? SELU_SCALE * x : SELU_SCALE * (SELU_ALPHA * (expf(x) - 1.f));
}

// ---------------- CSR build ----------------
__global__ void k_count(const int* __restrict__ dst, int* __restrict__ counts){
    int e = blockIdx.x * 256 + threadIdx.x;
    if (e < N_EDGES) atomicAdd(&counts[dst[e]], 1);
}

__global__ void k_local_scan(const int* __restrict__ counts, int* __restrict__ local_off,
                             int* __restrict__ graph_tot){
    __shared__ int s[128];
    int g = blockIdx.x, t = threadIdx.x;
    int v = (t < NPG) ? counts[g * NPG + t] : 0;
    s[t] = v; __syncthreads();
    for (int o = 1; o < 128; o <<= 1){
        int x = (t >= o) ? s[t - o] : 0;
        __syncthreads();
        s[t] += x;
        __syncthreads();
    }
    if (t < NPG) local_off[g * NPG + t] = s[t] - v;   // exclusive
    if (t == 127) graph_tot[g] = s[127];
}

__global__ void k_graph_scan(const int* __restrict__ graph_tot, int* __restrict__ graph_base){
    __shared__ int s[512];
    int t = threadIdx.x;
    int v = (t < N_GRAPHS) ? graph_tot[t] : 0;
    s[t] = v; __syncthreads();
    for (int o = 1; o < 512; o <<= 1){
        int x = (t >= o) ? s[t - o] : 0;
        __syncthreads();
        s[t] += x;
        __syncthreads();
    }
    if (t < N_GRAPHS) graph_base[t] = s[t] - v;       // exclusive
}

__global__ void k_off(const int* __restrict__ local_off, const int* __restrict__ graph_base,
                      int* __restrict__ node_off, int* __restrict__ write_ptr){
    int n = blockIdx.x * 256 + threadIdx.x;
    if (n < N_NODES){
        int v = local_off[n] + graph_base[n / NPG];
        node_off[n] = v;
        write_ptr[n] = v;
    }
}

__global__ void k_scatter(const int* __restrict__ src, const int* __restrict__ dst,
                          int* __restrict__ write_ptr, int* __restrict__ csr){
    int e = blockIdx.x * 256 + threadIdx.x;
    if (e < N_EDGES){
        int d = dst[e];
        int pos = atomicAdd(&write_ptr[d], 1);
        csr[pos] = src[e];
    }
}

// ---------------- GraphNorm ----------------
__global__ void k_gnorm(const float* __restrict__ x, const float* __restrict__ w,
                        const float* __restrict__ b, const float* __restrict__ ms,
                        float* __restrict__ y){
    __shared__ float sx[NPG * F_IN];
    __shared__ float red[16][16];
    __shared__ float meanS[16], varS[16];
    int g = blockIdx.x, t = threadIdx.x;
    for (int idx = t; idx < NPG * F_IN; idx += 256) sx[idx] = x[g * NPG * F_IN + idx];
    __syncthreads();
    int f = t & 15, grp = t >> 4;
    float p = 0.f;
    for (int i = grp; i < NPG; i += 16) p += sx[i * 16 + f];
    red[grp][f] = p; __syncthreads();
    if (t < 16){
        float s = 0.f;
        for (int i = 0; i < 16; i++) s += red[i][t];
        meanS[t] = s * (1.f / 100.f);
    }
    __syncthreads();
    float mm = meanS[f] * ms[f];
    p = 0.f;
    for (int i = grp; i < NPG; i += 16){ float v = sx[i * 16 + f] - mm; p += v * v; }
    red[grp][f] = p; __syncthreads();
    if (t < 16){
        float s = 0.f;
        for (int i = 0; i < 16; i++) s += red[i][t];
        varS[t] = s * (1.f / 100.f);
    }
    __syncthreads();
    for (int idx = t; idx < NPG * F_IN; idx += 256){
        int ff = idx & 15;
        float v = sx[idx] - meanS[ff] * ms[ff];
        y[g * NPG * F_IN + idx] = w[ff] * v * rsqrtf(varS[ff] + 1e-5f) + b[ff];
    }
}

// ---------------- tiled fp32 GEMM: Y[N,OUT] = X[N,K] @ W[K,OUT] ----------------
__global__ void k_gemm_tiled(const float* __restrict__ X, const float* __restrict__ W,
                             float* __restrict__ Y, int N, int K, int OUT){
    __shared__ float As[16][68];
    __shared__ float Bs[16][68];
    int t = threadIdx.x;
    int r0 = blockIdx.y * 64;
    int c0 = blockIdx.x * 64;
    int tx = t & 15, ty = t >> 4;
    float acc[4][4];
    #pragma unroll
    for (int i = 0; i < 4; i++)
        #pragma unroll
        for (int j = 0; j < 4; j++) acc[i][j] = 0.f;

    int lk = t & 15;
    int lm0 = t >> 4;
    int ln = t & 63;
    int lkb = t >> 6;

    for (int kt = 0; kt < K; kt += 16){
        #pragma unroll
        for (int i = 0; i < 4; i++){
            int m = lm0 + i * 16;
            int row = r0 + m;
            As[lk][m] = (row < N) ? X[row * K + kt + lk] : 0.f;
        }
        #pragma unroll
        for (int i = 0; i < 4; i++){
            int k = lkb + i * 4;
            Bs[k][ln] = W[(kt + k) * OUT + c0 + ln];
        }
        __syncthreads();
        #pragma unroll
        for (int k = 0; k < 16; k++){
            float4 a = *(const float4*)&As[k][ty * 4];
            float4 b = *(const float4*)&Bs[k][tx * 4];
            float av[4] = {a.x, a.y, a.z, a.w};
            float bv[4] = {b.x, b.y, b.z, b.w};
            #pragma unroll
            for (int i = 0; i < 4; i++)
                #pragma unroll
                for (int j = 0; j < 4; j++) acc[i][j] += av[i] * bv[j];
        }
        __syncthreads();
    }
    #pragma unroll
    for (int i = 0; i < 4; i++){
        int row = r0 + ty * 4 + i;
        if (row < N){
            float4 v = make_float4(acc[i][0], acc[i][1], acc[i][2], acc[i][3]);
            *(float4*)&Y[row * OUT + c0 + tx * 4] = v;
        }
    }
}

// ---------------- attention logits ----------------
__global__ void k_att4(const float* __restrict__ h, const float* __restrict__ as,
                       const float* __restrict__ ad, float* __restrict__ asrc,
                       float* __restrict__ adst){
    int wave = threadIdx.x >> 6, lane = threadIdx.x & 63;
    int n = blockIdx.x * 4 + wave;
    if (n >= N_NODES) return;
    float ps[4], pd[4];
    #pragma unroll
    for (int hh = 0; hh < 4; hh++){
        float v = h[n * 256 + hh * 64 + lane];
        ps[hh] = v * as[hh * 64 + lane];
        pd[hh] = v * ad[hh * 64 + lane];
    }
    #pragma unroll
    for (int o = 32; o >= 1; o >>= 1){
        #pragma unroll
        for (int hh = 0; hh < 4; hh++){
            ps[hh] += __shfl_xor(ps[hh], o);
            pd[hh] += __shfl_xor(pd[hh], o);
        }
    }
    if (lane == 0){
        *(float4*)&asrc[n * 4] = make_float4(ps[0], ps[1], ps[2], ps[3]);
        *(float4*)&adst[n * 4] = make_float4(pd[0], pd[1], pd[2], pd[3]);
    }
}

__global__ void k_att1(const float* __restrict__ h, const float* __restrict__ as,
                       const float* __restrict__ ad, float* __restrict__ asrc,
                       float* __restrict__ adst){
    int wave = threadIdx.x >> 6, lane = threadIdx.x & 63;
    int n = blockIdx.x * 4 + wave;
    if (n >= N_NODES) return;
    float v = h[n * 64 + lane];
    float ps = v * as[lane];
    float pd = v * ad[lane];
    #pragma unroll
    for (int o = 32; o >= 1; o >>= 1){
        ps += __shfl_xor(ps, o);
        pd += __shfl_xor(pd, o);
    }
    if (lane == 0){ asrc[n] = ps; adst[n] = pd; }
}

// ---------------- attention weights (one THREAD per dst node) ----------------
// H=4. Computes unnormalized w per edge (stored to ew), self weight, and 1/sum.
__global__ void k_alpha4(const float* __restrict__ asrc, const float* __restrict__ adst,
                         const int* __restrict__ csr, const int* __restrict__ noff,
                         const int* __restrict__ cnt,
                         float* __restrict__ ew, float* __restrict__ wself,
                         float* __restrict__ rsum){
    int d = blockIdx.x * 256 + threadIdx.x;
    if (d >= N_NODES) return;
    float4 ad = *(const float4*)&adst[d * 4];
    float4 asf = *(const float4*)&asrc[d * 4];
    float e0 = lrelu(asf.x + ad.x), e1 = lrelu(asf.y + ad.y);
    float e2 = lrelu(asf.z + ad.z), e3 = lrelu(asf.w + ad.w);
    float m0 = e0, m1 = e1, m2 = e2, m3 = e3;
    int beg = noff[d], n = cnt[d];
    for (int j = 0; j < n; j++){
        int s = csr[beg + j];
        float4 av = *(const float4*)&asrc[s * 4];
        m0 = fmaxf(m0, lrelu(av.x + ad.x));
        m1 = fmaxf(m1, lrelu(av.y + ad.y));
        m2 = fmaxf(m2, lrelu(av.z + ad.z));
        m3 = fmaxf(m3, lrelu(av.w + ad.w));
    }
    float w0 = expf(e0 - m0), w1 = expf(e1 - m1), w2 = expf(e2 - m2), w3 = expf(e3 - m3);
    float s0 = w0, s1 = w1, s2 = w2, s3 = w3;
    for (int j = 0; j < n; j++){
        int s = csr[beg + j];
        float4 av = *(const float4*)&asrc[s * 4];
        float v0 = expf(lrelu(av.x + ad.x) - m0);
        float v1 = expf(lrelu(av.y + ad.y) - m1);
        float v2 = expf(lrelu(av.z + ad.z) - m2);
        float v3 = expf(lrelu(av.w + ad.w) - m3);
        *(float4*)&ew[(beg + j) * 4] = make_float4(v0, v1, v2, v3);
        s0 += v0; s1 += v1; s2 += v2; s3 += v3;
    }
    *(float4*)&wself[d * 4] = make_float4(w0, w1, w2, w3);
    *(float4*)&rsum[d * 4] = make_float4(1.f / s0, 1.f / s1, 1.f / s2, 1.f / s3);
}

// H=1.
__global__ void k_alpha1(const float* __restrict__ asrc, const float* __restrict__ adst,
                         const int* __restrict__ csr, const int* __restrict__ noff,
                         const int* __restrict__ cnt,
                         float* __restrict__ ew, float* __restrict__ wself,
                         float* __restrict__ rsum){
    int d = blockIdx.x * 256 + threadIdx.x;
    if (d >= N_NODES) return;
    float ad = adst[d];
    float eself = lrelu(asrc[d] + ad);
    float m = eself;
    int beg = noff[d], n = cnt[d];
    for (int j = 0; j < n; j++){
        int s = csr[beg + j];
        m = fmaxf(m, lrelu(asrc[s] + ad));
    }
    float w = expf(eself - m);
    float sum = w;
    for (int j = 0; j < n; j++){
        int s = csr[beg + j];
        float v = expf(lrelu(asrc[s] + ad) - m);
        ew[beg + j] = v;
        sum += v;
    }
    wself[d] = w;
    rsum[d] = 1.f / sum;
}

// ---------------- weighted aggregation (one WAVE per dst node) ----------------
// H=4: acc = wself*h[d] + sum_j ew_j*h[src_j]; out = acc*rsum + bias, optional ELU.
__global__ void k_aggw4(const float* __restrict__ h, const float* __restrict__ ew,
                        const float* __restrict__ wself, const float* __restrict__ rsum,
                        const int* __restrict__ csr, const int* __restrict__ noff,
                        const int* __restrict__ cnt, const float* __restrict__ bias,
                        float* __restrict__ out, int do_elu){
    int wave = threadIdx.x >> 6, lane = threadIdx.x & 63;
    int d = blockIdx.x * 4 + wave;
    if (d >= N_NODES) return;
    float4 ws = *(const float4*)&wself[d * 4];
    int dbase = d * 256 + lane;
    float a0 = ws.x * h[dbase];
    float a1 = ws.y * h[dbase + 64];
    float a2 = ws.z * h[dbase + 128];
    float a3 = ws.w * h[dbase + 192];
    int beg = noff[d], n = cnt[d];
    for (int j = 0; j < n; j++){
        int s = csr[beg + j];
        float4 w = *(const float4*)&ew[(beg + j) * 4];
        int base = s * 256 + lane;
        a0 += w.x * h[base];
        a1 += w.y * h[base + 64];
        a2 += w.z * h[base + 128];
        a3 += w.w * h[base + 192];
    }
    float4 rs = *(const float4*)&rsum[d * 4];
    float o0 = a0 * rs.x + bias[lane];
    float o1 = a1 * rs.y + bias[64 + lane];
    float o2 = a2 * rs.z + bias[128 + lane];
    float o3 = a3 * rs.w + bias[192 + lane];
    if (do_elu){ o0 = eluf(o0); o1 = eluf(o1); o2 = eluf(o2); o3 = eluf(o3); }
    out[dbase] = o0; out[dbase + 64] = o1; out[dbase + 128] = o2; out[dbase + 192] = o3;
}

// H=1, no ELU (conv3).
__global__ void k_aggw1(const float* __restrict__ h, const float* __restrict__ ew,
                        const float* __restrict__ wself, const float* __restrict__ rsum,
                        const int* __restrict__ csr, const int* __restrict__ noff,
                        const int* __restrict__ cnt, const float* __restrict__ bias,
                        float* __restrict__ out){
    int wave = threadIdx.x >> 6, lane = threadIdx.x & 63;
    int d = blockIdx.x * 4 + wave;
    if (d >= N_NODES) return;
    float acc = wself[d] * h[d * 64 + lane];
    int beg = noff[d], n = cnt[d];
    for (int j = 0; j < n; j++){
        int s = csr[beg + j];
        acc += ew[beg + j] * h[s * 64 + lane];
    }
    out[d * 64 + lane] = acc * rsum[d] + bias[lane];
}

// ---------------- pooling + BN + dense head ----------------
__global__ void k_head(const float* __restrict__ x3, const float* __restrict__ gin,
                       const float* __restrict__ bn_g, const float* __restrict__ bn_b,
                       const float* __restrict__ bn_m, const float* __restrict__ bn_v,
                       const float* __restrict__ Wd1, const float* __restrict__ bd1,
                       const float* __restrict__ Wd2, const float* __restrict__ bd2,
                       const float* __restrict__ Wo, const float* __restrict__ bo,
                       float* __restrict__ out){
    __shared__ float red[256];
    __shared__ float gv[68];
    __shared__ float g2[64];
    __shared__ float g3[64];
    int g = blockIdx.x, t = threadIdx.x;
    int c = t & 63, grp = t >> 6;
    float p = 0.f;
    for (int i = grp; i < NPG; i += 4) p += x3[(g * NPG + i) * 64 + c];
    red[t] = p; __syncthreads();
    if (t < 64){
        float s = red[t] + red[t + 64] + red[t + 128] + red[t + 192];
        float mean = s * (1.f / 100.f);
        gv[t] = (mean - bn_m[t]) * rsqrtf(bn_v[t] + 1e-5f) * bn_g[t] + bn_b[t];
    } else if (t < 68){
        int j = t - 64;
        float v = gin[g * 4 + j];
        gv[t] = (v - bn_m[t]) * rsqrtf(bn_v[t] + 1e-5f) * bn_g[t] + bn_b[t];
    }
    __syncthreads();
    if (t < 64){
        float s = bd1[t];
        for (int i = 0; i < 68; i++) s += gv[i] * Wd1[i * 64 + t];
        g2[t] = seluf(s);
    }
    __syncthreads();
    if (t < 64){
        float s = bd2[t];
        for (int i = 0; i < 64; i++) s += g2[i] * Wd2[i * 64 + t];
        g3[t] = seluf(s);
    }
    __syncthreads();
    if (t == 0){
        float l0 = bo[0], l1 = bo[1];
        for (int i = 0; i < 64; i++){ l0 += g3[i] * Wo[i * 2]; l1 += g3[i] * Wo[i * 2 + 1]; }
        float mx = fmaxf(l0, l1);
        float e0 = expf(l0 - mx), e1 = expf(l1 - mx);
        float inv = 1.f / (e0 + e1);
        out[g * 2] = e0 * inv;
        out[g * 2 + 1] = e1 * inv;
    }
}

extern "C" void kernel_launch(void* const* d_in, const int* in_sizes, int n_in,
                              void* d_out, int out_size, void* d_ws, size_t ws_size,
                              hipStream_t stream){
    const float* x   = (const float*)d_in[0];
    const int*   ei  = (const int*)d_in[1];
    const float* gin = (const float*)d_in[2];
    const float* gn_w = (const float*)d_in[4];
    const float* gn_b = (const float*)d_in[5];
    const float* gn_ms = (const float*)d_in[6];
    const float* W1 = (const float*)d_in[7];
    const float* as1 = (const float*)d_in[8];
    const float* ad1 = (const float*)d_in[9];
    const float* b1 = (const float*)d_in[10];
    const float* W2 = (const float*)d_in[11];
    const float* as2 = (const float*)d_in[12];
    const float* ad2 = (const float*)d_in[13];
    const float* b2 = (const float*)d_in[14];
    const float* W3 = (const float*)d_in[15];
    const float* as3 = (const float*)d_in[16];
    const float* ad3 = (const float*)d_in[17];
    const float* b3 = (const float*)d_in[18];
    const float* bn_g = (const float*)d_in[19];
    const float* bn_b = (const float*)d_in[20];
    const float* bn_m = (const float*)d_in[21];
    const float* bn_v = (const float*)d_in[22];
    const float* Wd1 = (const float*)d_in[23];
    const float* bd1 = (const float*)d_in[24];
    const float* Wd2 = (const float*)d_in[25];
    const float* bd2 = (const float*)d_in[26];
    const float* Wo = (const float*)d_in[27];
    const float* bo = (const float*)d_in[28];
    float* out = (float*)d_out;

    const int* src = ei;
    const int* dst = ei + N_EDGES;

    char* ws = (char*)d_ws;
    size_t off = 0;
    auto alloc = [&](size_t bytes) -> void* {
        void* p = ws + off;
        off = (off + bytes + 255) & ~(size_t)255;
        return p;
    };
    int* counts     = (int*)alloc((size_t)N_NODES * 4);
    int* local_off  = (int*)alloc((size_t)N_NODES * 4);
    int* node_off   = (int*)alloc((size_t)N_NODES * 4);
    int* write_ptr  = (int*)alloc((size_t)N_NODES * 4);
    int* graph_tot  = (int*)alloc(512 * 4);
    int* graph_base = (int*)alloc(512 * 4);
    int* csr        = (int*)alloc((size_t)N_EDGES * 4);
    float* y        = (float*)alloc((size_t)N_NODES * F_IN * 4);
    float* asrc     = (float*)alloc((size_t)N_NODES * 4 * 4);
    float* adst     = (float*)alloc((size_t)N_NODES * 4 * 4);
    float* ew       = (float*)alloc((size_t)N_EDGES * 4 * 4);
    float* wself    = (float*)alloc((size_t)N_NODES * 4 * 4);
    float* rsum     = (float*)alloc((size_t)N_NODES * 4 * 4);
    float* bufA     = (float*)alloc((size_t)N_NODES * 256 * 4);
    float* bufB     = (float*)alloc((size_t)N_NODES * 256 * 4);

    // --- CSR build ---
    hipMemsetAsync(counts, 0, (size_t)N_NODES * 4, stream);
    k_count<<<(N_EDGES + 255) / 256, 256, 0, stream>>>(dst, counts);
    k_local_scan<<<N_GRAPHS, 128, 0, stream>>>(counts, local_off, graph_tot);
    k_graph_scan<<<1, 512, 0, stream>>>(graph_tot, graph_base);
    k_off<<<(N_NODES + 255) / 256, 256, 0, stream>>>(local_off, graph_base, node_off, write_ptr);
    k_scatter<<<(N_EDGES + 255) / 256, 256, 0, stream>>>(src, dst, write_ptr, csr);

    // --- GraphNorm ---
    k_gnorm<<<N_GRAPHS, 256, 0, stream>>>(x, gn_w, gn_b, gn_ms, y);

    int nwb = (N_NODES + 3) / 4;       // 4 waves/block, one wave per node
    int ntb = (N_NODES + 255) / 256;   // one thread per node
    dim3 gemm_grid4(4, (N_NODES + 63) / 64);
    dim3 gemm_grid1(1, (N_NODES + 63) / 64);

    // --- conv1: 16 -> 4x64, ELU ---
    k_gemm_tiled<<<gemm_grid4, 256, 0, stream>>>(y, W1, bufA, N_NODES, 16, 256);
    k_att4<<<nwb, 256, 0, stream>>>(bufA, as1, ad1, asrc, adst);
    k_alpha4<<<ntb, 256, 0, stream>>>(asrc, adst, csr, node_off, counts, ew, wself, rsum);
    k_aggw4<<<nwb, 256, 0, stream>>>(bufA, ew, wself, rsum, csr, node_off, counts, b1, bufB, 1);

    // --- conv2: 256 -> 4x64, ELU ---
    k_gemm_tiled<<<gemm_grid4, 256, 0, stream>>>(bufB, W2, bufA, N_NODES, 256, 256);
    k_att4<<<nwb, 256, 0, stream>>>(bufA, as2, ad2, asrc, adst);
    k_alpha4<<<ntb, 256, 0, stream>>>(asrc, adst, csr, node_off, counts, ew, wself, rsum);
    k_aggw4<<<nwb, 256, 0, stream>>>(bufA, ew, wself, rsum, csr, node_off, counts, b2, bufB, 1);

    // --- conv3: 256 -> 64, no ELU ---
    k_gemm_tiled<<<gemm_grid1, 256, 0, stream>>>(bufB, W3, bufA, N_NODES, 256, 64);
    k_att1<<<nwb, 256, 0, stream>>>(bufA, as3, ad3, asrc, adst);
    k_alpha1<<<ntb, 256, 0, stream>>>(asrc, adst, csr, node_off, counts, ew, wself, rsum);
    k_aggw1<<<nwb, 256, 0, stream>>>(bufA, ew, wself, rsum, csr, node_off, counts, b3, bufB);

    // --- pool + BN + dense head + softmax ---
    k_head<<<N_GRAPHS, 256, 0, stream>>>(bufB, gin, bn_g, bn_b, bn_m, bn_v,
                                         Wd1, bd1, Wd2, bd2, Wo, bo, out);
}

// Round 3
// 543.176 us; speedup vs baseline: 1.6001x; 1.1961x over previous
//
#include <hip/hip_runtime.h>
#include <math.h>

#define N_NODES 50000
#define N_ROWS_PAD 50048   // 782 * 64
#define N_GRAPHS 500
#define NPG 100
#define N_EDGES 500000
#define F_IN 16
#define HID 64

#define SELU_SCALE 1.0507009873554804934193349852946f
#define SELU_ALPHA 1.6732632423543772848170429916717f

typedef __attribute__((ext_vector_type(8))) short short8;
typedef __attribute__((ext_vector_type(4))) float floatx4;

__device__ __forceinline__ float lrelu(float x){ return x > 0.f ? x : 0.2f * x; }
__device__ __forceinline__ float eluf(float x){ return x > 0.f ? x : expf(x) - 1.f; }
__device__ __forceinline__ float seluf(float x){
    return x > 0.f ? SELU_SCALE * x : SELU_SCALE * (SELU_ALPHA * (expf(x) - 1.f));
}
__device__ __forceinline__ unsigned short f2bf(float x){
    unsigned u = __float_as_uint(x);
    return (unsigned short)((u + 0x7FFFu + ((u >> 16) & 1u)) >> 16);
}

// ---------------- CSR build ----------------
__global__ void k_count(const int* __restrict__ dst, int* __restrict__ counts){
    int e = blockIdx.x * 256 + threadIdx.x;
    if (e < N_EDGES) atomicAdd(&counts[dst[e]], 1);
}

__global__ void k_local_scan(const int* __restrict__ counts, int* __restrict__ local_off,
                             int* __restrict__ graph_tot){
    __shared__ int s[128];
    int g = blockIdx.x, t = threadIdx.x;
    int v = (t < NPG) ? counts[g * NPG + t] : 0;
    s[t] = v; __syncthreads();
    for (int o = 1; o < 128; o <<= 1){
        int x = (t >= o) ? s[t - o] : 0;
        __syncthreads();
        s[t] += x;
        __syncthreads();
    }
    if (t < NPG) local_off[g * NPG + t] = s[t] - v;   // exclusive
    if (t == 127) graph_tot[g] = s[127];
}

__global__ void k_graph_scan(const int* __restrict__ graph_tot, int* __restrict__ graph_base){
    __shared__ int s[512];
    int t = threadIdx.x;
    int v = (t < N_GRAPHS) ? graph_tot[t] : 0;
    s[t] = v; __syncthreads();
    for (int o = 1; o < 512; o <<= 1){
        int x = (t >= o) ? s[t - o] : 0;
        __syncthreads();
        s[t] += x;
        __syncthreads();
    }
    if (t < N_GRAPHS) graph_base[t] = s[t] - v;       // exclusive
}

__global__ void k_off(const int* __restrict__ local_off, const int* __restrict__ graph_base,
                      int* __restrict__ node_off, int* __restrict__ write_ptr){
    int n = blockIdx.x * 256 + threadIdx.x;
    if (n < N_NODES){
        int v = local_off[n] + graph_base[n / NPG];
        node_off[n] = v;
        write_ptr[n] = v;
    }
}

__global__ void k_scatter(const int* __restrict__ src, const int* __restrict__ dst,
                          int* __restrict__ write_ptr, int* __restrict__ csr){
    int e = blockIdx.x * 256 + threadIdx.x;
    if (e < N_EDGES){
        int d = dst[e];
        int pos = atomicAdd(&write_ptr[d], 1);
        csr[pos] = src[e];
    }
}

// ---------------- GraphNorm ----------------
__global__ void k_gnorm(const float* __restrict__ x, const float* __restrict__ w,
                        const float* __restrict__ b, const float* __restrict__ ms,
                        float* __restrict__ y){
    __shared__ float sx[NPG * F_IN];
    __shared__ float red[16][16];
    __shared__ float meanS[16], varS[16];
    int g = blockIdx.x, t = threadIdx.x;
    for (int idx = t; idx < NPG * F_IN; idx += 256) sx[idx] = x[g * NPG * F_IN + idx];
    __syncthreads();
    int f = t & 15, grp = t >> 4;
    float p = 0.f;
    for (int i = grp; i < NPG; i += 16) p += sx[i * 16 + f];
    red[grp][f] = p; __syncthreads();
    if (t < 16){
        float s = 0.f;
        for (int i = 0; i < 16; i++) s += red[i][t];
        meanS[t] = s * (1.f / 100.f);
    }
    __syncthreads();
    float mm = meanS[f] * ms[f];
    p = 0.f;
    for (int i = grp; i < NPG; i += 16){ float v = sx[i * 16 + f] - mm; p += v * v; }
    red[grp][f] = p; __syncthreads();
    if (t < 16){
        float s = 0.f;
        for (int i = 0; i < 16; i++) s += red[i][t];
        varS[t] = s * (1.f / 100.f);
    }
    __syncthreads();
    for (int idx = t; idx < NPG * F_IN; idx += 256){
        int ff = idx & 15;
        float v = sx[idx] - meanS[ff] * ms[ff];
        y[g * NPG * F_IN + idx] = w[ff] * v * rsqrtf(varS[ff] + 1e-5f) + b[ff];
    }
}

// ---------------- fp32 tiled GEMM (conv1 only, K=16) ----------------
__global__ void k_gemm_tiled(const float* __restrict__ X, const float* __restrict__ W,
                             float* __restrict__ Y, int N, int K, int OUT){
    __shared__ float As[16][68];
    __shared__ float Bs[16][68];
    int t = threadIdx.x;
    int r0 = blockIdx.y * 64;
    int c0 = blockIdx.x * 64;
    int tx = t & 15, ty = t >> 4;
    float acc[4][4];
    #pragma unroll
    for (int i = 0; i < 4; i++)
        #pragma unroll
        for (int j = 0; j < 4; j++) acc[i][j] = 0.f;

    int lk = t & 15;
    int lm0 = t >> 4;
    int ln = t & 63;
    int lkb = t >> 6;

    for (int kt = 0; kt < K; kt += 16){
        #pragma unroll
        for (int i = 0; i < 4; i++){
            int m = lm0 + i * 16;
            int row = r0 + m;
            As[lk][m] = (row < N) ? X[row * K + kt + lk] : 0.f;
        }
        #pragma unroll
        for (int i = 0; i < 4; i++){
            int k = lkb + i * 4;
            Bs[k][ln] = W[(kt + k) * OUT + c0 + ln];
        }
        __syncthreads();
        #pragma unroll
        for (int k = 0; k < 16; k++){
            float4 a = *(const float4*)&As[k][ty * 4];
            float4 b = *(const float4*)&Bs[k][tx * 4];
            float av[4] = {a.x, a.y, a.z, a.w};
            float bv[4] = {b.x, b.y, b.z, b.w};
            #pragma unroll
            for (int i = 0; i < 4; i++)
                #pragma unroll
                for (int j = 0; j < 4; j++) acc[i][j] += av[i] * bv[j];
        }
        __syncthreads();
    }
    #pragma unroll
    for (int i = 0; i < 4; i++){
        int row = r0 + ty * 4 + i;
        if (row < N){
            float4 v = make_float4(acc[i][0], acc[i][1], acc[i][2], acc[i][3]);
            *(float4*)&Y[row * OUT + c0 + tx * 4] = v;
        }
    }
}

// ---------------- W pack to MFMA-B-fragment order + bf16 ----------------
// Wp[((k>>3)*OUT + n)*8 + (k&7)] = bf16(W[k*OUT + n])
__global__ void k_pack_w(const float* __restrict__ W, unsigned short* __restrict__ Wp,
                         int K, int OUT){
    int idx = blockIdx.x * 256 + threadIdx.x;
    if (idx >= K * OUT) return;
    int k = idx / OUT, n = idx - k * OUT;
    Wp[(((k >> 3) * OUT) + n) * 8 + (k & 7)] = f2bf(W[idx]);
}

// ---------------- bf16 MFMA GEMM: Y[N,OUT] = Xb[N,K] @ W[K,OUT] ----------------
// Xb: bf16 row-major (rows padded to N_ROWS_PAD). Wp: packed as above. Y: fp32.
// Block 256 thr = 4 waves. Tile 64 rows x 64 cols; wave w -> rows [w*16, w*16+16).
__global__ void k_gemm_mfma(const unsigned short* __restrict__ Xb,
                            const unsigned short* __restrict__ Wp,
                            float* __restrict__ Y, int N, int K, int OUT){
    int t = threadIdx.x;
    int wave = t >> 6, lane = t & 63;
    int quad = lane >> 4, ln = lane & 15;
    int r0 = blockIdx.y * 64 + wave * 16;
    int c0 = blockIdx.x * 64;

    floatx4 acc[4];
    #pragma unroll
    for (int f = 0; f < 4; f++) acc[f] = (floatx4){0.f, 0.f, 0.f, 0.f};

    const unsigned short* aptr = Xb + (size_t)(r0 + ln) * K + quad * 8;
    for (int kt = 0; kt < K; kt += 32){
        short8 a = *(const short8*)(aptr + kt);
        int kc = (kt >> 3) + quad;   // k-chunk index
        #pragma unroll
        for (int f = 0; f < 4; f++){
            short8 b = *(const short8*)(Wp + ((size_t)kc * OUT + c0 + f * 16 + ln) * 8);
            acc[f] = __builtin_amdgcn_mfma_f32_16x16x32_bf16(a, b, acc[f], 0, 0, 0);
        }
    }
    int rowb = r0 + quad * 4;
    #pragma unroll
    for (int f = 0; f < 4; f++){
        int col = c0 + f * 16 + ln;
        #pragma unroll
        for (int rg = 0; rg < 4; rg++){
            int row = rowb + rg;
            if (row < N) Y[(size_t)row * OUT + col] = acc[f][rg];
        }
    }
}

// ---------------- attention logits ----------------
__global__ void k_att4(const float* __restrict__ h, const float* __restrict__ as,
                       const float* __restrict__ ad, float* __restrict__ asrc,
                       float* __restrict__ adst){
    int wave = threadIdx.x >> 6, lane = threadIdx.x & 63;
    int n = blockIdx.x * 4 + wave;
    if (n >= N_NODES) return;
    float ps[4], pd[4];
    #pragma unroll
    for (int hh = 0; hh < 4; hh++){
        float v = h[n * 256 + hh * 64 + lane];
        ps[hh] = v * as[hh * 64 + lane];
        pd[hh] = v * ad[hh * 64 + lane];
    }
    #pragma unroll
    for (int o = 32; o >= 1; o >>= 1){
        #pragma unroll
        for (int hh = 0; hh < 4; hh++){
            ps[hh] += __shfl_xor(ps[hh], o);
            pd[hh] += __shfl_xor(pd[hh], o);
        }
    }
    if (lane == 0){
        *(float4*)&asrc[n * 4] = make_float4(ps[0], ps[1], ps[2], ps[3]);
        *(float4*)&adst[n * 4] = make_float4(pd[0], pd[1], pd[2], pd[3]);
    }
}

__global__ void k_att1(const float* __restrict__ h, const float* __restrict__ as,
                       const float* __restrict__ ad, float* __restrict__ asrc,
                       float* __restrict__ adst){
    int wave = threadIdx.x >> 6, lane = threadIdx.x & 63;
    int n = blockIdx.x * 4 + wave;
    if (n >= N_NODES) return;
    float v = h[n * 64 + lane];
    float ps = v * as[lane];
    float pd = v * ad[lane];
    #pragma unroll
    for (int o = 32; o >= 1; o >>= 1){
        ps += __shfl_xor(ps, o);
        pd += __shfl_xor(pd, o);
    }
    if (lane == 0){ asrc[n] = ps; adst[n] = pd; }
}

// ---------------- attention weights (one THREAD per dst node) ----------------
__global__ void k_alpha4(const float* __restrict__ asrc, const float* __restrict__ adst,
                         const int* __restrict__ csr, const int* __restrict__ noff,
                         const int* __restrict__ cnt,
                         float* __restrict__ ew, float* __restrict__ wself,
                         float* __restrict__ rsum){
    int d = blockIdx.x * 256 + threadIdx.x;
    if (d >= N_NODES) return;
    float4 ad = *(const float4*)&adst[d * 4];
    float4 asf = *(const float4*)&asrc[d * 4];
    float e0 = lrelu(asf.x + ad.x), e1 = lrelu(asf.y + ad.y);
    float e2 = lrelu(asf.z + ad.z), e3 = lrelu(asf.w + ad.w);
    float m0 = e0, m1 = e1, m2 = e2, m3 = e3;
    int beg = noff[d], n = cnt[d];
    for (int j = 0; j < n; j++){
        int s = csr[beg + j];
        float4 av = *(const float4*)&asrc[s * 4];
        m0 = fmaxf(m0, lrelu(av.x + ad.x));
        m1 = fmaxf(m1, lrelu(av.y + ad.y));
        m2 = fmaxf(m2, lrelu(av.z + ad.z));
        m3 = fmaxf(m3, lrelu(av.w + ad.w));
    }
    float w0 = expf(e0 - m0), w1 = expf(e1 - m1), w2 = expf(e2 - m2), w3 = expf(e3 - m3);
    float s0 = w0, s1 = w1, s2 = w2, s3 = w3;
    for (int j = 0; j < n; j++){
        int s = csr[beg + j];
        float4 av = *(const float4*)&asrc[s * 4];
        float v0 = expf(lrelu(av.x + ad.x) - m0);
        float v1 = expf(lrelu(av.y + ad.y) - m1);
        float v2 = expf(lrelu(av.z + ad.z) - m2);
        float v3 = expf(lrelu(av.w + ad.w) - m3);
        *(float4*)&ew[(beg + j) * 4] = make_float4(v0, v1, v2, v3);
        s0 += v0; s1 += v1; s2 += v2; s3 += v3;
    }
    *(float4*)&wself[d * 4] = make_float4(w0, w1, w2, w3);
    *(float4*)&rsum[d * 4] = make_float4(1.f / s0, 1.f / s1, 1.f / s2, 1.f / s3);
}

__global__ void k_alpha1(const float* __restrict__ asrc, const float* __restrict__ adst,
                         const int* __restrict__ csr, const int* __restrict__ noff,
                         const int* __restrict__ cnt,
                         float* __restrict__ ew, float* __restrict__ wself,
                         float* __restrict__ rsum){
    int d = blockIdx.x * 256 + threadIdx.x;
    if (d >= N_NODES) return;
    float ad = adst[d];
    float eself = lrelu(asrc[d] + ad);
    float m = eself;
    int beg = noff[d], n = cnt[d];
    for (int j = 0; j < n; j++){
        int s = csr[beg + j];
        m = fmaxf(m, lrelu(asrc[s] + ad));
    }
    float w = expf(eself - m);
    float sum = w;
    for (int j = 0; j < n; j++){
        int s = csr[beg + j];
        float v = expf(lrelu(asrc[s] + ad) - m);
        ew[beg + j] = v;
        sum += v;
    }
    wself[d] = w;
    rsum[d] = 1.f / sum;
}

// ---------------- weighted aggregation (one WAVE per dst node) ----------------
// H=4. Output written as bf16 (feeds next layer's MFMA GEMM). ELU applied.
__global__ void k_aggw4(const float* __restrict__ h, const float* __restrict__ ew,
                        const float* __restrict__ wself, const float* __restrict__ rsum,
                        const int* __restrict__ csr, const int* __restrict__ noff,
                        const int* __restrict__ cnt, const float* __restrict__ bias,
                        unsigned short* __restrict__ out_bf){
    int wave = threadIdx.x >> 6, lane = threadIdx.x & 63;
    int d = blockIdx.x * 4 + wave;
    if (d >= N_NODES) return;
    float4 ws = *(const float4*)&wself[d * 4];
    int dbase = d * 256 + lane;
    float a0 = ws.x * h[dbase];
    float a1 = ws.y * h[dbase + 64];
    float a2 = ws.z * h[dbase + 128];
    float a3 = ws.w * h[dbase + 192];
    int beg = noff[d], n = cnt[d];
    for (int j = 0; j < n; j++){
        int s = csr[beg + j];
        float4 w = *(const float4*)&ew[(beg + j) * 4];
        int base = s * 256 + lane;
        a0 += w.x * h[base];
        a1 += w.y * h[base + 64];
        a2 += w.z * h[base + 128];
        a3 += w.w * h[base + 192];
    }
    float4 rs = *(const float4*)&rsum[d * 4];
    float o0 = eluf(a0 * rs.x + bias[lane]);
    float o1 = eluf(a1 * rs.y + bias[64 + lane]);
    float o2 = eluf(a2 * rs.z + bias[128 + lane]);
    float o3 = eluf(a3 * rs.w + bias[192 + lane]);
    out_bf[dbase] = f2bf(o0);
    out_bf[dbase + 64] = f2bf(o1);
    out_bf[dbase + 128] = f2bf(o2);
    out_bf[dbase + 192] = f2bf(o3);
}

// H=1, fp32 out, no ELU (conv3 -> head).
__global__ void k_aggw1(const float* __restrict__ h, const float* __restrict__ ew,
                        const float* __restrict__ wself, const float* __restrict__ rsum,
                        const int* __restrict__ csr, const int* __restrict__ noff,
                        const int* __restrict__ cnt, const float* __restrict__ bias,
                        float* __restrict__ out){
    int wave = threadIdx.x >> 6, lane = threadIdx.x & 63;
    int d = blockIdx.x * 4 + wave;
    if (d >= N_NODES) return;
    float acc = wself[d] * h[d * 64 + lane];
    int beg = noff[d], n = cnt[d];
    for (int j = 0; j < n; j++){
        int s = csr[beg + j];
        acc += ew[beg + j] * h[s * 64 + lane];
    }
    out[d * 64 + lane] = acc * rsum[d] + bias[lane];
}

// ---------------- pooling + BN + dense head ----------------
__global__ void k_head(const float* __restrict__ x3, const float* __restrict__ gin,
                       const float* __restrict__ bn_g, const float* __restrict__ bn_b,
                       const float* __restrict__ bn_m, const float* __restrict__ bn_v,
                       const float* __restrict__ Wd1, const float* __restrict__ bd1,
                       const float* __restrict__ Wd2, const float* __restrict__ bd2,
                       const float* __restrict__ Wo, const float* __restrict__ bo,
                       float* __restrict__ out){
    __shared__ float red[256];
    __shared__ float gv[68];
    __shared__ float g2[64];
    __shared__ float g3[64];
    int g = blockIdx.x, t = threadIdx.x;
    int c = t & 63, grp = t >> 6;
    float p = 0.f;
    for (int i = grp; i < NPG; i += 4) p += x3[(g * NPG + i) * 64 + c];
    red[t] = p; __syncthreads();
    if (t < 64){
        float s = red[t] + red[t + 64] + red[t + 128] + red[t + 192];
        float mean = s * (1.f / 100.f);
        gv[t] = (mean - bn_m[t]) * rsqrtf(bn_v[t] + 1e-5f) * bn_g[t] + bn_b[t];
    } else if (t < 68){
        int j = t - 64;
        float v = gin[g * 4 + j];
        gv[t] = (v - bn_m[t]) * rsqrtf(bn_v[t] + 1e-5f) * bn_g[t] + bn_b[t];
    }
    __syncthreads();
    if (t < 64){
        float s = bd1[t];
        for (int i = 0; i < 68; i++) s += gv[i] * Wd1[i * 64 + t];
        g2[t] = seluf(s);
    }
    __syncthreads();
    if (t < 64){
        float s = bd2[t];
        for (int i = 0; i < 64; i++) s += g2[i] * Wd2[i * 64 + t];
        g3[t] = seluf(s);
    }
    __syncthreads();
    if (t == 0){
        float l0 = bo[0], l1 = bo[1];
        for (int i = 0; i < 64; i++){ l0 += g3[i] * Wo[i * 2]; l1 += g3[i] * Wo[i * 2 + 1]; }
        float mx = fmaxf(l0, l1);
        float e0 = expf(l0 - mx), e1 = expf(l1 - mx);
        float inv = 1.f / (e0 + e1);
        out[g * 2] = e0 * inv;
        out[g * 2 + 1] = e1 * inv;
    }
}

extern "C" void kernel_launch(void* const* d_in, const int* in_sizes, int n_in,
                              void* d_out, int out_size, void* d_ws, size_t ws_size,
                              hipStream_t stream){
    const float* x   = (const float*)d_in[0];
    const int*   ei  = (const int*)d_in[1];
    const float* gin = (const float*)d_in[2];
    const float* gn_w = (const float*)d_in[4];
    const float* gn_b = (const float*)d_in[5];
    const float* gn_ms = (const float*)d_in[6];
    const float* W1 = (const float*)d_in[7];
    const float* as1 = (const float*)d_in[8];
    const float* ad1 = (const float*)d_in[9];
    const float* b1 = (const float*)d_in[10];
    const float* W2 = (const float*)d_in[11];
    const float* as2 = (const float*)d_in[12];
    const float* ad2 = (const float*)d_in[13];
    const float* b2 = (const float*)d_in[14];
    const float* W3 = (const float*)d_in[15];
    const float* as3 = (const float*)d_in[16];
    const float* ad3 = (const float*)d_in[17];
    const float* b3 = (const float*)d_in[18];
    const float* bn_g = (const float*)d_in[19];
    const float* bn_b = (const float*)d_in[20];
    const float* bn_m = (const float*)d_in[21];
    const float* bn_v = (const float*)d_in[22];
    const float* Wd1 = (const float*)d_in[23];
    const float* bd1 = (const float*)d_in[24];
    const float* Wd2 = (const float*)d_in[25];
    const float* bd2 = (const float*)d_in[26];
    const float* Wo = (const float*)d_in[27];
    const float* bo = (const float*)d_in[28];
    float* out = (float*)d_out;

    const int* src = ei;
    const int* dst = ei + N_EDGES;

    char* ws = (char*)d_ws;
    size_t off = 0;
    auto alloc = [&](size_t bytes) -> void* {
        void* p = ws + off;
        off = (off + bytes + 255) & ~(size_t)255;
        return p;
    };
    int* counts     = (int*)alloc((size_t)N_NODES * 4);
    int* local_off  = (int*)alloc((size_t)N_NODES * 4);
    int* node_off   = (int*)alloc((size_t)N_NODES * 4);
    int* write_ptr  = (int*)alloc((size_t)N_NODES * 4);
    int* graph_tot  = (int*)alloc(512 * 4);
    int* graph_base = (int*)alloc(512 * 4);
    int* csr        = (int*)alloc((size_t)N_EDGES * 4);
    float* y        = (float*)alloc((size_t)N_NODES * F_IN * 4);
    float* asrc     = (float*)alloc((size_t)N_NODES * 4 * 4);
    float* adst     = (float*)alloc((size_t)N_NODES * 4 * 4);
    float* ew       = (float*)alloc((size_t)N_EDGES * 4 * 4);
    float* wself    = (float*)alloc((size_t)N_NODES * 4 * 4);
    float* rsum     = (float*)alloc((size_t)N_NODES * 4 * 4);
    unsigned short* wp2 = (unsigned short*)alloc((size_t)256 * 256 * 2);
    unsigned short* wp3 = (unsigned short*)alloc((size_t)256 * 64 * 2);
    float* bufA     = (float*)alloc((size_t)N_NODES * 256 * 4);          // h (fp32)
    unsigned short* xb = (unsigned short*)alloc((size_t)N_ROWS_PAD * 256 * 2); // bf16 GEMM input
    float* bufC     = (float*)alloc((size_t)N_NODES * HID * 4);          // conv3 gemm out
    float* bufD     = (float*)alloc((size_t)N_NODES * HID * 4);          // conv3 agg out

    // --- CSR build ---
    hipMemsetAsync(counts, 0, (size_t)N_NODES * 4, stream);
    k_count<<<(N_EDGES + 255) / 256, 256, 0, stream>>>(dst, counts);
    k_local_scan<<<N_GRAPHS, 128, 0, stream>>>(counts, local_off, graph_tot);
    k_graph_scan<<<1, 512, 0, stream>>>(graph_tot, graph_base);
    k_off<<<(N_NODES + 255) / 256, 256, 0, stream>>>(local_off, graph_base, node_off, write_ptr);
    k_scatter<<<(N_EDGES + 255) / 256, 256, 0, stream>>>(src, dst, write_ptr, csr);

    // --- weight packs (bf16, MFMA-B order) ---
    k_pack_w<<<(256 * 256 + 255) / 256, 256, 0, stream>>>(W2, wp2, 256, 256);
    k_pack_w<<<(256 * 64 + 255) / 256, 256, 0, stream>>>(W3, wp3, 256, 64);

    // --- GraphNorm ---
    k_gnorm<<<N_GRAPHS, 256, 0, stream>>>(x, gn_w, gn_b, gn_ms, y);

    int nwb = (N_NODES + 3) / 4;       // 4 waves/block, one wave per node
    int ntb = (N_NODES + 255) / 256;   // one thread per node
    dim3 gemm_grid4(4, (N_NODES + 63) / 64);
    dim3 mfma_grid4(4, N_ROWS_PAD / 64);
    dim3 mfma_grid1(1, N_ROWS_PAD / 64);

    // --- conv1: 16 -> 4x64, ELU (fp32 GEMM; K=16 too small for MFMA win) ---
    k_gemm_tiled<<<gemm_grid4, 256, 0, stream>>>(y, W1, bufA, N_NODES, 16, 256);
    k_att4<<<nwb, 256, 0, stream>>>(bufA, as1, ad1, asrc, adst);
    k_alpha4<<<ntb, 256, 0, stream>>>(asrc, adst, csr, node_off, counts, ew, wself, rsum);
    k_aggw4<<<nwb, 256, 0, stream>>>(bufA, ew, wself, rsum, csr, node_off, counts, b1, xb);

    // --- conv2: 256 -> 4x64, ELU (bf16 MFMA GEMM) ---
    k_gemm_mfma<<<mfma_grid4, 256, 0, stream>>>(xb, wp2, bufA, N_NODES, 256, 256);
    k_att4<<<nwb, 256, 0, stream>>>(bufA, as2, ad2, asrc, adst);
    k_alpha4<<<ntb, 256, 0, stream>>>(asrc, adst, csr, node_off, counts, ew, wself, rsum);
    k_aggw4<<<nwb, 256, 0, stream>>>(bufA, ew, wself, rsum, csr, node_off, counts, b2, xb);

    // --- conv3: 256 -> 64, no ELU (bf16 MFMA GEMM) ---
    k_gemm_mfma<<<mfma_grid1, 256, 0, stream>>>(xb, wp3, bufC, N_NODES, 256, 64);
    k_att1<<<nwb, 256, 0, stream>>>(bufC, as3, ad3, asrc, adst);
    k_alpha1<<<ntb, 256, 0, stream>>>(asrc, adst, csr, node_off, counts, ew, wself, rsum);
    k_aggw1<<<nwb, 256, 0, stream>>>(bufC, ew, wself, rsum, csr, node_off, counts, b3, bufD);

    // --- pool + BN + dense head + softmax ---
    k_head<<<N_GRAPHS, 256, 0, stream>>>(bufD, gin, bn_g, bn_b, bn_m, bn_v,
                                         Wd1, bd1, Wd2, bd2, Wo, bo, out);
}

// Round 4
// 432.975 us; speedup vs baseline: 2.0073x; 1.2545x over previous
//
#include <hip/hip_runtime.h>
#include <math.h>

#define N_NODES 50000
#define N_ROWS_PAD 50048   // 782 * 64
#define N_GRAPHS 500
#define NPG 100
#define N_EDGES 500000
#define F_IN 16
#define HID 64
#define EW_CAP 1792        // max intra-graph edges (mean 1000, sigma ~32 -> 25 sigma)

#define SELU_SCALE 1.0507009873554804934193349852946f
#define SELU_ALPHA 1.6732632423543772848170429916717f

typedef __attribute__((ext_vector_type(8))) short short8;
typedef __attribute__((ext_vector_type(4))) float floatx4;

__device__ __forceinline__ float lrelu(float x){ return x > 0.f ? x : 0.2f * x; }
__device__ __forceinline__ float eluf(float x){ return x > 0.f ? x : expf(x) - 1.f; }
__device__ __forceinline__ float seluf(float x){
    return x > 0.f ? SELU_SCALE * x : SELU_SCALE * (SELU_ALPHA * (expf(x) - 1.f));
}
__device__ __forceinline__ unsigned short f2bf(float x){
    unsigned u = __float_as_uint(x);
    return (unsigned short)((u + 0x7FFFu + ((u >> 16) & 1u)) >> 16);
}

// ---------------- CSR build ----------------
__global__ void k_count(const int* __restrict__ dst, int* __restrict__ counts){
    int e = blockIdx.x * 256 + threadIdx.x;
    if (e < N_EDGES) atomicAdd(&counts[dst[e]], 1);
}

__global__ void k_local_scan(const int* __restrict__ counts, int* __restrict__ local_off,
                             int* __restrict__ graph_tot){
    __shared__ int s[128];
    int g = blockIdx.x, t = threadIdx.x;
    int v = (t < NPG) ? counts[g * NPG + t] : 0;
    s[t] = v; __syncthreads();
    for (int o = 1; o < 128; o <<= 1){
        int x = (t >= o) ? s[t - o] : 0;
        __syncthreads();
        s[t] += x;
        __syncthreads();
    }
    if (t < NPG) local_off[g * NPG + t] = s[t] - v;   // exclusive
    if (t == 127) graph_tot[g] = s[127];
}

__global__ void k_graph_scan(const int* __restrict__ graph_tot, int* __restrict__ graph_base){
    __shared__ int s[512];
    int t = threadIdx.x;
    int v = (t < N_GRAPHS) ? graph_tot[t] : 0;
    s[t] = v; __syncthreads();
    for (int o = 1; o < 512; o <<= 1){
        int x = (t >= o) ? s[t - o] : 0;
        __syncthreads();
        s[t] += x;
        __syncthreads();
    }
    if (t < N_GRAPHS) graph_base[t] = s[t] - v;       // exclusive
}

__global__ void k_off(const int* __restrict__ local_off, const int* __restrict__ graph_base,
                      int* __restrict__ node_off, int* __restrict__ write_ptr){
    int n = blockIdx.x * 256 + threadIdx.x;
    if (n < N_NODES){
        int v = local_off[n] + graph_base[n / NPG];
        node_off[n] = v;
        write_ptr[n] = v;
    }
}

__global__ void k_scatter(const int* __restrict__ src, const int* __restrict__ dst,
                          int* __restrict__ write_ptr, int* __restrict__ csr){
    int e = blockIdx.x * 256 + threadIdx.x;
    if (e < N_EDGES){
        int d = dst[e];
        int pos = atomicAdd(&write_ptr[d], 1);
        csr[pos] = src[e];
    }
}

// ---------------- GraphNorm ----------------
__global__ void k_gnorm(const float* __restrict__ x, const float* __restrict__ w,
                        const float* __restrict__ b, const float* __restrict__ ms,
                        float* __restrict__ y){
    __shared__ float sx[NPG * F_IN];
    __shared__ float red[16][16];
    __shared__ float meanS[16], varS[16];
    int g = blockIdx.x, t = threadIdx.x;
    for (int idx = t; idx < NPG * F_IN; idx += 256) sx[idx] = x[g * NPG * F_IN + idx];
    __syncthreads();
    int f = t & 15, grp = t >> 4;
    float p = 0.f;
    for (int i = grp; i < NPG; i += 16) p += sx[i * 16 + f];
    red[grp][f] = p; __syncthreads();
    if (t < 16){
        float s = 0.f;
        for (int i = 0; i < 16; i++) s += red[i][t];
        meanS[t] = s * (1.f / 100.f);
    }
    __syncthreads();
    float mm = meanS[f] * ms[f];
    p = 0.f;
    for (int i = grp; i < NPG; i += 16){ float v = sx[i * 16 + f] - mm; p += v * v; }
    red[grp][f] = p; __syncthreads();
    if (t < 16){
        float s = 0.f;
        for (int i = 0; i < 16; i++) s += red[i][t];
        varS[t] = s * (1.f / 100.f);
    }
    __syncthreads();
    for (int idx = t; idx < NPG * F_IN; idx += 256){
        int ff = idx & 15;
        float v = sx[idx] - meanS[ff] * ms[ff];
        y[g * NPG * F_IN + idx] = w[ff] * v * rsqrtf(varS[ff] + 1e-5f) + b[ff];
    }
}

// ---------------- fp32 tiled GEMM (conv1 only, K=16) ----------------
__global__ void k_gemm_tiled(const float* __restrict__ X, const float* __restrict__ W,
                             float* __restrict__ Y, int N, int K, int OUT){
    __shared__ float As[16][68];
    __shared__ float Bs[16][68];
    int t = threadIdx.x;
    int r0 = blockIdx.y * 64;
    int c0 = blockIdx.x * 64;
    int tx = t & 15, ty = t >> 4;
    float acc[4][4];
    #pragma unroll
    for (int i = 0; i < 4; i++)
        #pragma unroll
        for (int j = 0; j < 4; j++) acc[i][j] = 0.f;

    int lk = t & 15;
    int lm0 = t >> 4;
    int ln = t & 63;
    int lkb = t >> 6;

    for (int kt = 0; kt < K; kt += 16){
        #pragma unroll
        for (int i = 0; i < 4; i++){
            int m = lm0 + i * 16;
            int row = r0 + m;
            As[lk][m] = (row < N) ? X[row * K + kt + lk] : 0.f;
        }
        #pragma unroll
        for (int i = 0; i < 4; i++){
            int k = lkb + i * 4;
            Bs[k][ln] = W[(kt + k) * OUT + c0 + ln];
        }
        __syncthreads();
        #pragma unroll
        for (int k = 0; k < 16; k++){
            float4 a = *(const float4*)&As[k][ty * 4];
            float4 b = *(const float4*)&Bs[k][tx * 4];
            float av[4] = {a.x, a.y, a.z, a.w};
            float bv[4] = {b.x, b.y, b.z, b.w};
            #pragma unroll
            for (int i = 0; i < 4; i++)
                #pragma unroll
                for (int j = 0; j < 4; j++) acc[i][j] += av[i] * bv[j];
        }
        __syncthreads();
    }
    #pragma unroll
    for (int i = 0; i < 4; i++){
        int row = r0 + ty * 4 + i;
        if (row < N){
            float4 v = make_float4(acc[i][0], acc[i][1], acc[i][2], acc[i][3]);
            *(float4*)&Y[row * OUT + c0 + tx * 4] = v;
        }
    }
}

// ---------------- W pack to MFMA-B-fragment order + bf16 ----------------
__global__ void k_pack_w(const float* __restrict__ W, unsigned short* __restrict__ Wp,
                         int K, int OUT){
    int idx = blockIdx.x * 256 + threadIdx.x;
    if (idx >= K * OUT) return;
    int k = idx / OUT, n = idx - k * OUT;
    Wp[(((k >> 3) * OUT) + n) * 8 + (k & 7)] = f2bf(W[idx]);
}

// ---------------- bf16 MFMA GEMM ----------------
__global__ void k_gemm_mfma(const unsigned short* __restrict__ Xb,
                            const unsigned short* __restrict__ Wp,
                            float* __restrict__ Y, int N, int K, int OUT){
    int t = threadIdx.x;
    int wave = t >> 6, lane = t & 63;
    int quad = lane >> 4, ln = lane & 15;
    int r0 = blockIdx.y * 64 + wave * 16;
    int c0 = blockIdx.x * 64;

    floatx4 acc[4];
    #pragma unroll
    for (int f = 0; f < 4; f++) acc[f] = (floatx4){0.f, 0.f, 0.f, 0.f};

    const unsigned short* aptr = Xb + (size_t)(r0 + ln) * K + quad * 8;
    for (int kt = 0; kt < K; kt += 32){
        short8 a = *(const short8*)(aptr + kt);
        int kc = (kt >> 3) + quad;
        #pragma unroll
        for (int f = 0; f < 4; f++){
            short8 b = *(const short8*)(Wp + ((size_t)kc * OUT + c0 + f * 16 + ln) * 8);
            acc[f] = __builtin_amdgcn_mfma_f32_16x16x32_bf16(a, b, acc[f], 0, 0, 0);
        }
    }
    int rowb = r0 + quad * 4;
    #pragma unroll
    for (int f = 0; f < 4; f++){
        int col = c0 + f * 16 + ln;
        #pragma unroll
        for (int rg = 0; rg < 4; rg++){
            int row = rowb + rg;
            if (row < N) Y[(size_t)row * OUT + col] = acc[f][rg];
        }
    }
}

// ---------------- fused GAT layer (att + softmax + aggregate), one block per graph ----
// H=4, C=64/head (256 total). h fp32 in, bf16 out (feeds next MFMA GEMM), ELU applied.
__global__ void __launch_bounds__(256, 1)
k_fused4(const float* __restrict__ h, const float* __restrict__ as,
         const float* __restrict__ ad, const float* __restrict__ bias,
         const int* __restrict__ csr, const int* __restrict__ noff,
         const int* __restrict__ cnt, unsigned short* __restrict__ out_bf){
    __shared__ __align__(16) float hl[NPG * 256];      // 102400 B
    __shared__ __align__(16) float ewl[EW_CAP * 4];    // 28672 B
    __shared__ int   csl[EW_CAP];                      // 7168 B
    __shared__ float asrcl[NPG * 4], adstl[NPG * 4];
    __shared__ float wselfl[NPG * 4], rsuml[NPG * 4];
    __shared__ float asl[256], adl[256];
    __shared__ int offl[NPG], cntl[NPG];

    int g = blockIdx.x, t = threadIdx.x;
    int base = g * NPG;

    // stage h block (100 rows x 256 cols fp32, contiguous) into LDS
    const float4* hsrc = (const float4*)(h + (size_t)base * 256);
    float4* hd = (float4*)hl;
    for (int i = t; i < NPG * 64; i += 256) hd[i] = hsrc[i];
    asl[t] = as[t]; adl[t] = ad[t];
    if (t < NPG){ offl[t] = noff[base + t]; cntl[t] = cnt[base + t]; }
    __syncthreads();

    // stage this graph's CSR slice (localized node ids)
    int ebeg = offl[0];
    int etot = offl[NPG - 1] + cntl[NPG - 1] - ebeg;
    int eln = etot < EW_CAP ? etot : EW_CAP;
    for (int i = t; i < eln; i += 256) csl[i] = csr[ebeg + i] - base;

    // attention logits: 400 (node,head) pairs, channel-staggered to avoid conflicts
    for (int idx = t; idx < NPG * 4; idx += 256){
        int n = idx >> 2, hh = idx & 3;
        int c0 = t & 63;
        const float* hr = &hl[n * 256 + hh * 64];
        const float* ar = &asl[hh * 64];
        const float* dr = &adl[hh * 64];
        float ps = 0.f, pd = 0.f;
        #pragma unroll 8
        for (int i = 0; i < 64; i++){
            int c = (c0 + i) & 63;
            float v = hr[c];
            ps += v * ar[c]; pd += v * dr[c];
        }
        asrcl[idx] = ps; adstl[idx] = pd;
    }
    __syncthreads();

    // softmax weights: one thread per dst node
    if (t < NPG){
        float4 adv = *(const float4*)&adstl[t * 4];
        float4 asv = *(const float4*)&asrcl[t * 4];
        float e0 = lrelu(asv.x + adv.x), e1 = lrelu(asv.y + adv.y);
        float e2 = lrelu(asv.z + adv.z), e3 = lrelu(asv.w + adv.w);
        float m0 = e0, m1 = e1, m2 = e2, m3 = e3;
        int ebg = offl[t] - ebeg, n = cntl[t];
        for (int j = 0; j < n; j++){
            int s = csl[ebg + j];
            float4 av = *(const float4*)&asrcl[s * 4];
            m0 = fmaxf(m0, lrelu(av.x + adv.x));
            m1 = fmaxf(m1, lrelu(av.y + adv.y));
            m2 = fmaxf(m2, lrelu(av.z + adv.z));
            m3 = fmaxf(m3, lrelu(av.w + adv.w));
        }
        float w0 = expf(e0 - m0), w1 = expf(e1 - m1), w2 = expf(e2 - m2), w3 = expf(e3 - m3);
        float s0 = w0, s1 = w1, s2 = w2, s3 = w3;
        for (int j = 0; j < n; j++){
            int s = csl[ebg + j];
            float4 av = *(const float4*)&asrcl[s * 4];
            float v0 = expf(lrelu(av.x + adv.x) - m0);
            float v1 = expf(lrelu(av.y + adv.y) - m1);
            float v2 = expf(lrelu(av.z + adv.z) - m2);
            float v3 = expf(lrelu(av.w + adv.w) - m3);
            *(float4*)&ewl[(ebg + j) * 4] = make_float4(v0, v1, v2, v3);
            s0 += v0; s1 += v1; s2 += v2; s3 += v3;
        }
        *(float4*)&wselfl[t * 4] = make_float4(w0, w1, w2, w3);
        *(float4*)&rsuml[t * 4] = make_float4(1.f / s0, 1.f / s1, 1.f / s2, 1.f / s3);
    }
    __syncthreads();

    // aggregate: one wave per dst node (stride 4)
    int wave = t >> 6, lane = t & 63;
    float b0 = bias[lane], b1 = bias[64 + lane], b2 = bias[128 + lane], b3 = bias[192 + lane];
    for (int d = wave; d < NPG; d += 4){
        float4 ws = *(const float4*)&wselfl[d * 4];
        float4 rs = *(const float4*)&rsuml[d * 4];
        const float* hr = &hl[d * 256];
        float a0 = ws.x * hr[lane];
        float a1 = ws.y * hr[64 + lane];
        float a2 = ws.z * hr[128 + lane];
        float a3 = ws.w * hr[192 + lane];
        int ebg = offl[d] - ebeg, n = cntl[d];
        for (int j = 0; j < n; j++){
            int s = csl[ebg + j];
            float4 w = *(const float4*)&ewl[(ebg + j) * 4];
            const float* hs = &hl[s * 256];
            a0 += w.x * hs[lane];
            a1 += w.y * hs[64 + lane];
            a2 += w.z * hs[128 + lane];
            a3 += w.w * hs[192 + lane];
        }
        size_t ob = (size_t)(base + d) * 256 + lane;
        out_bf[ob]       = f2bf(eluf(a0 * rs.x + b0));
        out_bf[ob + 64]  = f2bf(eluf(a1 * rs.y + b1));
        out_bf[ob + 128] = f2bf(eluf(a2 * rs.z + b2));
        out_bf[ob + 192] = f2bf(eluf(a3 * rs.w + b3));
    }
}

// H=1, C=64. fp32 out, no ELU (conv3 -> head).
__global__ void __launch_bounds__(256, 1)
k_fused1(const float* __restrict__ h, const float* __restrict__ as,
         const float* __restrict__ ad, const float* __restrict__ bias,
         const int* __restrict__ csr, const int* __restrict__ noff,
         const int* __restrict__ cnt, float* __restrict__ out){
    __shared__ __align__(16) float hl[NPG * 64];       // 25600 B
    __shared__ float ewl[EW_CAP];                      // 7168 B
    __shared__ int   csl[EW_CAP];                      // 7168 B
    __shared__ float asrcl[NPG], adstl[NPG];
    __shared__ float wselfl[NPG], rsuml[NPG];
    __shared__ float asl[64], adl[64];
    __shared__ int offl[NPG], cntl[NPG];

    int g = blockIdx.x, t = threadIdx.x;
    int base = g * NPG;

    const float4* hsrc = (const float4*)(h + (size_t)base * 64);
    float4* hd = (float4*)hl;
    for (int i = t; i < NPG * 16; i += 256) hd[i] = hsrc[i];
    if (t < 64){ asl[t] = as[t]; adl[t] = ad[t]; }
    if (t < NPG){ offl[t] = noff[base + t]; cntl[t] = cnt[base + t]; }
    __syncthreads();

    int ebeg = offl[0];
    int etot = offl[NPG - 1] + cntl[NPG - 1] - ebeg;
    int eln = etot < EW_CAP ? etot : EW_CAP;
    for (int i = t; i < eln; i += 256) csl[i] = csr[ebeg + i] - base;

    for (int n = t; n < NPG; n += 256){
        int c0 = t & 63;
        const float* hr = &hl[n * 64];
        float ps = 0.f, pd = 0.f;
        #pragma unroll 8
        for (int i = 0; i < 64; i++){
            int c = (c0 + i) & 63;
            float v = hr[c];
            ps += v * asl[c]; pd += v * adl[c];
        }
        asrcl[n] = ps; adstl[n] = pd;
    }
    __syncthreads();

    if (t < NPG){
        float adv = adstl[t];
        float e = lrelu(asrcl[t] + adv);
        float m = e;
        int ebg = offl[t] - ebeg, n = cntl[t];
        for (int j = 0; j < n; j++)
            m = fmaxf(m, lrelu(asrcl[csl[ebg + j]] + adv));
        float w = expf(e - m);
        float sum = w;
        for (int j = 0; j < n; j++){
            float v = expf(lrelu(asrcl[csl[ebg + j]] + adv) - m);
            ewl[ebg + j] = v;
            sum += v;
        }
        wselfl[t] = w;
        rsuml[t] = 1.f / sum;
    }
    __syncthreads();

    int wave = t >> 6, lane = t & 63;
    float bl = bias[lane];
    for (int d = wave; d < NPG; d += 4){
        float acc = wselfl[d] * hl[d * 64 + lane];
        int ebg = offl[d] - ebeg, n = cntl[d];
        for (int j = 0; j < n; j++){
            int s = csl[ebg + j];
            acc += ewl[ebg + j] * hl[s * 64 + lane];
        }
        out[(size_t)(base + d) * 64 + lane] = acc * rsuml[d] + bl;
    }
}

// ---------------- pooling + BN + dense head ----------------
__global__ void k_head(const float* __restrict__ x3, const float* __restrict__ gin,
                       const float* __restrict__ bn_g, const float* __restrict__ bn_b,
                       const float* __restrict__ bn_m, const float* __restrict__ bn_v,
                       const float* __restrict__ Wd1, const float* __restrict__ bd1,
                       const float* __restrict__ Wd2, const float* __restrict__ bd2,
                       const float* __restrict__ Wo, const float* __restrict__ bo,
                       float* __restrict__ out){
    __shared__ float red[256];
    __shared__ float gv[68];
    __shared__ float g2[64];
    __shared__ float g3[64];
    int g = blockIdx.x, t = threadIdx.x;
    int c = t & 63, grp = t >> 6;
    float p = 0.f;
    for (int i = grp; i < NPG; i += 4) p += x3[(g * NPG + i) * 64 + c];
    red[t] = p; __syncthreads();
    if (t < 64){
        float s = red[t] + red[t + 64] + red[t + 128] + red[t + 192];
        float mean = s * (1.f / 100.f);
        gv[t] = (mean - bn_m[t]) * rsqrtf(bn_v[t] + 1e-5f) * bn_g[t] + bn_b[t];
    } else if (t < 68){
        int j = t - 64;
        float v = gin[g * 4 + j];
        gv[t] = (v - bn_m[t]) * rsqrtf(bn_v[t] + 1e-5f) * bn_g[t] + bn_b[t];
    }
    __syncthreads();
    if (t < 64){
        float s = bd1[t];
        for (int i = 0; i < 68; i++) s += gv[i] * Wd1[i * 64 + t];
        g2[t] = seluf(s);
    }
    __syncthreads();
    if (t < 64){
        float s = bd2[t];
        for (int i = 0; i < 64; i++) s += g2[i] * Wd2[i * 64 + t];
        g3[t] = seluf(s);
    }
    __syncthreads();
    if (t == 0){
        float l0 = bo[0], l1 = bo[1];
        for (int i = 0; i < 64; i++){ l0 += g3[i] * Wo[i * 2]; l1 += g3[i] * Wo[i * 2 + 1]; }
        float mx = fmaxf(l0, l1);
        float e0 = expf(l0 - mx), e1 = expf(l1 - mx);
        float inv = 1.f / (e0 + e1);
        out[g * 2] = e0 * inv;
        out[g * 2 + 1] = e1 * inv;
    }
}

extern "C" void kernel_launch(void* const* d_in, const int* in_sizes, int n_in,
                              void* d_out, int out_size, void* d_ws, size_t ws_size,
                              hipStream_t stream){
    const float* x   = (const float*)d_in[0];
    const int*   ei  = (const int*)d_in[1];
    const float* gin = (const float*)d_in[2];
    const float* gn_w = (const float*)d_in[4];
    const float* gn_b = (const float*)d_in[5];
    const float* gn_ms = (const float*)d_in[6];
    const float* W1 = (const float*)d_in[7];
    const float* as1 = (const float*)d_in[8];
    const float* ad1 = (const float*)d_in[9];
    const float* b1 = (const float*)d_in[10];
    const float* W2 = (const float*)d_in[11];
    const float* as2 = (const float*)d_in[12];
    const float* ad2 = (const float*)d_in[13];
    const float* b2 = (const float*)d_in[14];
    const float* W3 = (const float*)d_in[15];
    const float* as3 = (const float*)d_in[16];
    const float* ad3 = (const float*)d_in[17];
    const float* b3 = (const float*)d_in[18];
    const float* bn_g = (const float*)d_in[19];
    const float* bn_b = (const float*)d_in[20];
    const float* bn_m = (const float*)d_in[21];
    const float* bn_v = (const float*)d_in[22];
    const float* Wd1 = (const float*)d_in[23];
    const float* bd1 = (const float*)d_in[24];
    const float* Wd2 = (const float*)d_in[25];
    const float* bd2 = (const float*)d_in[26];
    const float* Wo = (const float*)d_in[27];
    const float* bo = (const float*)d_in[28];
    float* out = (float*)d_out;

    const int* src = ei;
    const int* dst = ei + N_EDGES;

    char* ws = (char*)d_ws;
    size_t off = 0;
    auto alloc = [&](size_t bytes) -> void* {
        void* p = ws + off;
        off = (off + bytes + 255) & ~(size_t)255;
        return p;
    };
    int* counts     = (int*)alloc((size_t)N_NODES * 4);
    int* local_off  = (int*)alloc((size_t)N_NODES * 4);
    int* node_off   = (int*)alloc((size_t)N_NODES * 4);
    int* write_ptr  = (int*)alloc((size_t)N_NODES * 4);
    int* graph_tot  = (int*)alloc(512 * 4);
    int* graph_base = (int*)alloc(512 * 4);
    int* csr        = (int*)alloc((size_t)N_EDGES * 4);
    float* y        = (float*)alloc((size_t)N_NODES * F_IN * 4);
    unsigned short* wp2 = (unsigned short*)alloc((size_t)256 * 256 * 2);
    unsigned short* wp3 = (unsigned short*)alloc((size_t)256 * 64 * 2);
    float* bufA     = (float*)alloc((size_t)N_NODES * 256 * 4);          // h (fp32 GEMM out)
    unsigned short* xb = (unsigned short*)alloc((size_t)N_ROWS_PAD * 256 * 2); // bf16 GEMM input
    float* bufC     = (float*)alloc((size_t)N_NODES * HID * 4);          // conv3 gemm out
    float* bufD     = (float*)alloc((size_t)N_NODES * HID * 4);          // conv3 agg out

    // --- CSR build ---
    hipMemsetAsync(counts, 0, (size_t)N_NODES * 4, stream);
    k_count<<<(N_EDGES + 255) / 256, 256, 0, stream>>>(dst, counts);
    k_local_scan<<<N_GRAPHS, 128, 0, stream>>>(counts, local_off, graph_tot);
    k_graph_scan<<<1, 512, 0, stream>>>(graph_tot, graph_base);
    k_off<<<(N_NODES + 255) / 256, 256, 0, stream>>>(local_off, graph_base, node_off, write_ptr);
    k_scatter<<<(N_EDGES + 255) / 256, 256, 0, stream>>>(src, dst, write_ptr, csr);

    // --- weight packs (bf16, MFMA-B order) ---
    k_pack_w<<<(256 * 256 + 255) / 256, 256, 0, stream>>>(W2, wp2, 256, 256);
    k_pack_w<<<(256 * 64 + 255) / 256, 256, 0, stream>>>(W3, wp3, 256, 64);

    // --- GraphNorm ---
    k_gnorm<<<N_GRAPHS, 256, 0, stream>>>(x, gn_w, gn_b, gn_ms, y);

    dim3 gemm_grid4(4, (N_NODES + 63) / 64);
    dim3 mfma_grid4(4, N_ROWS_PAD / 64);
    dim3 mfma_grid1(1, N_ROWS_PAD / 64);

    // --- conv1: 16 -> 4x64, ELU ---
    k_gemm_tiled<<<gemm_grid4, 256, 0, stream>>>(y, W1, bufA, N_NODES, 16, 256);
    k_fused4<<<N_GRAPHS, 256, 0, stream>>>(bufA, as1, ad1, b1, csr, node_off, counts, xb);

    // --- conv2: 256 -> 4x64, ELU ---
    k_gemm_mfma<<<mfma_grid4, 256, 0, stream>>>(xb, wp2, bufA, N_NODES, 256, 256);
    k_fused4<<<N_GRAPHS, 256, 0, stream>>>(bufA, as2, ad2, b2, csr, node_off, counts, xb);

    // --- conv3: 256 -> 64, no ELU ---
    k_gemm_mfma<<<mfma_grid1, 256, 0, stream>>>(xb, wp3, bufC, N_NODES, 256, 64);
    k_fused1<<<N_GRAPHS, 256, 0, stream>>>(bufC, as3, ad3, b3, csr, node_off, counts, bufD);

    // --- pool + BN + dense head + softmax ---
    k_head<<<N_GRAPHS, 256, 0, stream>>>(bufD, gin, bn_g, bn_b, bn_m, bn_v,
                                         Wd1, bd1, Wd2, bd2, Wo, bo, out);
}